// Round 8
// baseline (852.402 us; speedup 1.0000x reference)
//
#include <hip/hip_runtime.h>

typedef unsigned short u16;
typedef __attribute__((ext_vector_type(8))) short short8;
typedef __attribute__((ext_vector_type(4))) float f32x4;

__device__ __forceinline__ u16 f32_to_bf16(float f) {
  unsigned u = __float_as_uint(f);
  u += 0x7fffu + ((u >> 16) & 1u);
  return (u16)(u >> 16);
}
__device__ __forceinline__ float bf16_to_f32(u16 h) {
  return __uint_as_float(((unsigned)h) << 16);
}

// async global->LDS, 16B per lane; lds dest = wave-uniform base + lane*16
#define GLD_LDS16(gp, lp)                                                  \
  __builtin_amdgcn_global_load_lds(                                        \
      (const __attribute__((address_space(1))) void*)(gp),                 \
      (__attribute__((address_space(3))) void*)(lp), 16, 0, 0)

#define WAITVM(n) asm volatile("s_waitcnt vmcnt(" #n ")" ::: "memory")

__device__ __forceinline__ void wg_barrier() {
  asm volatile("" ::: "memory");
  __builtin_amdgcn_s_barrier();
  asm volatile("" ::: "memory");
}

// ---------------- fused 4-weight f32 -> bf16 conversion ----------------
__global__ __launch_bounds__(256) void cvt4_f32_bf16(const float* __restrict__ s0,
                                                     const float* __restrict__ s1,
                                                     const float* __restrict__ s2,
                                                     const float* __restrict__ s3,
                                                     u16* __restrict__ d0,
                                                     u16* __restrict__ d1,
                                                     u16* __restrict__ d2,
                                                     u16* __restrict__ d3) {
  const float* s = blockIdx.y == 0 ? s0 : blockIdx.y == 1 ? s1 : blockIdx.y == 2 ? s2 : s3;
  u16* d = blockIdx.y == 0 ? d0 : blockIdx.y == 1 ? d1 : blockIdx.y == 2 ? d2 : d3;
  int i = blockIdx.x * 256 + threadIdx.x;  // 65536 float4 per tensor
  float4 v = ((const float4*)s)[i];
  uint2 r;
  r.x = (unsigned)f32_to_bf16(v.x) | ((unsigned)f32_to_bf16(v.y) << 16);
  r.y = (unsigned)f32_to_bf16(v.z) | ((unsigned)f32_to_bf16(v.w) << 16);
  ((uint2*)d)[i] = r;
}

// ---------------- GroupNorm stats: mean/rstd per (b,g) ----------------
__global__ __launch_bounds__(1024) void gn_stats(const float* __restrict__ x,
                                                 float2* __restrict__ stats) {
  int bg = blockIdx.x;
  const float* xp = x + (long)bg * 65536;
  int t = threadIdx.x;
  float s = 0.f, ss = 0.f;
  for (int i = t; i < 16384; i += 1024) {
    float4 v = ((const float4*)xp)[i];
    s += (v.x + v.y) + (v.z + v.w);
    ss += (v.x * v.x + v.y * v.y) + (v.z * v.z + v.w * v.w);
  }
#pragma unroll
  for (int o = 32; o; o >>= 1) { s += __shfl_xor(s, o); ss += __shfl_xor(ss, o); }
  __shared__ float rs[16], rq[16];
  int wave = t >> 6, lane = t & 63;
  if (lane == 0) { rs[wave] = s; rq[wave] = ss; }
  __syncthreads();
  if (wave == 0) {
    float a = lane < 16 ? rs[lane] : 0.f;
    float b = lane < 16 ? rq[lane] : 0.f;
#pragma unroll
    for (int o = 8; o; o >>= 1) { a += __shfl_xor(a, o); b += __shfl_xor(b, o); }
    if (lane == 0) {
      float mean = a * (1.f / 65536.f);
      float var = b * (1.f / 65536.f) - mean * mean;
      stats[bg] = make_float2(mean, rsqrtf(var + 1e-6f));
    }
  }
}

// ---------------- GroupNorm apply + transpose -> hT[B][4096][512] ----------------
__global__ __launch_bounds__(256) void gn_apply_t(const float* __restrict__ x,
                                                  const float* __restrict__ gw,
                                                  const float* __restrict__ gb,
                                                  const float2* __restrict__ stats,
                                                  u16* __restrict__ hT) {
  const int g = blockIdx.y, bb = blockIdx.z;
  const float2 st = stats[bb * 32 + g];
  const float mean = st.x, rstd = st.y;
  const float* xp = x + ((long)bb * 512 + g * 16) * 4096;
  u16* hp = hT + (long)bb * 4096 * 512 + g * 16;
  const int i = blockIdx.x * 1024 + threadIdx.x * 4;
#pragma unroll
  for (int half = 0; half < 2; ++half) {
    float w[8], bv[8];
#pragma unroll
    for (int c = 0; c < 8; ++c) {
      w[c] = gw[g * 16 + half * 8 + c] * rstd;
      bv[c] = gb[g * 16 + half * 8 + c];
    }
    float v[8][4];
#pragma unroll
    for (int c = 0; c < 8; ++c) {
      float4 f = *(const float4*)(xp + (long)(half * 8 + c) * 4096 + i);
      v[c][0] = f.x; v[c][1] = f.y; v[c][2] = f.z; v[c][3] = f.w;
    }
#pragma unroll
    for (int p = 0; p < 4; ++p) {
      u16 o[8];
#pragma unroll
      for (int c = 0; c < 8; ++c) o[c] = f32_to_bf16((v[c][p] - mean) * w[c] + bv[c]);
      *(int4*)(hp + (long)(i + p) * 512 + half * 8) = *(int4*)o;
    }
  }
}

// ---------------- 128x128 2-blocks/CU bf16 MFMA GEMM (B^T form) ----------------
// C[m][n] = sum_k A[m][k]*B[n][k].  256 threads = 4 waves (2M x 2N), wave
// tile 64x64 (acc 4x4).  BK=64, DEPTH=2 ring (64 KB LDS -> 2 independent
// blocks/CU: cross-block overlap fills barrier stalls).  One phase per
// K-tile: {stage(t+1); WAITVM(8) certify t; barrier; reads+MFMA (2 k-halves,
// no inner barrier); barrier}.  XOR-swizzled LDS (conflict-free by
// construction: slot ^= row&7).  setprio around MFMA.
// MODE 0: bf16 out (+biasM/biasN, scale)
// MODE 1: C = exp(S) bf16 (no max shift; |S| <~ 2) + per-row partial sums
//         over this block's 128 cols -> psum[z*32+bx][row]
// MODE 2: plain GEMM, epilogue * Sinv[row].
// SWZ 1: XCD band remap (xcd = id%8 heuristic; bijective for gy%8==0):
//        XCD c owns by-band [c*gy/8,(c+1)*gy/8) x all bx -> A-panel L2-local.
template <int MODE, int SWZ>
__global__ __launch_bounds__(256, 2) void gemm128v2(
    const u16* __restrict__ A0, long sA, int lda,
    const u16* __restrict__ B0, long sB, int ldb,
    u16* __restrict__ Cb, long sC, int ldc,
    const float* __restrict__ biasM, const float* __restrict__ biasN,
    float scale, int K,
    float* __restrict__ psum, const float* __restrict__ SinvP) {
  __shared__ __align__(16) u16 As[2][128 * 64];
  __shared__ __align__(16) u16 Bs[2][128 * 64];
  const u16* A = A0 + (long)blockIdx.z * sA;
  const u16* B = B0 + (long)blockIdx.z * sB;

  int bx = blockIdx.x, by = blockIdx.y;
  if (SWZ == 1) {
    const int id = bx + gridDim.x * by;
    const int c = id & 7, w = id >> 3;
    const int nb = gridDim.y >> 3;  // band rows per XCD
    by = c * nb + (w % nb);
    bx = w / nb;
  }
  const int m0 = by * 128, n0 = bx * 128;
  const int t = threadIdx.x;
  const int wave = t >> 6, lane = t & 63;
  const int wy = wave >> 1, wx = wave & 1;
  const int lr = lane & 15, q = lane >> 4;
  const int NT = K >> 6;  // K-tiles of 64

  // staging: row = 128 B = 8 16B-slots; LDS slot sl at row r holds global
  // k-chunk (sl ^ (r&7)).  Pre-swizzle GLOBAL source; LDS dest linear (DMA).
  long aoff[4], boff[4];
  int ldsb[4];
#pragma unroll
  for (int cc = 0; cc < 4; ++cc) {
    int idx = cc * 256 + t;
    int row = idx >> 3, sl = idx & 7;
    int qs = sl ^ (row & 7);
    aoff[cc] = (long)(m0 + row) * lda + qs * 8;
    boff[cc] = (long)(n0 + row) * ldb + qs * 8;
    ldsb[cc] = (cc * 256 + wave * 64) * 8;  // u16 units, wave-uniform
  }
  auto stageAB = [&](int tile, int buf) {
    const long kk = (long)tile << 6;
#pragma unroll
    for (int cc = 0; cc < 4; ++cc) GLD_LDS16(A + aoff[cc] + kk, &As[buf][ldsb[cc]]);
#pragma unroll
    for (int cc = 0; cc < 4; ++cc) GLD_LDS16(B + boff[cc] + kk, &Bs[buf][ldsb[cc]]);
  };

  // read-side swizzled slot offsets (u16); frag rows mult16+lr -> row&7=lr&7
  const int so0 = ((q ^ (lr & 7)) << 3);        // k-half 0: chunk q
  const int so1 = (((4 + q) ^ (lr & 7)) << 3);  // k-half 1: chunk 4+q
  const int arow = wy * 64, brow = wx * 64;

  f32x4 acc[4][4] = {};

  stageAB(0, 0);
  for (int tt = 0; tt < NT; ++tt) {
    if (tt + 1 < NT) {
      stageAB(tt + 1, (tt + 1) & 1);
      WAITVM(8);  // certify tile tt (its 8 loads are the oldest)
    } else {
      WAITVM(0);
    }
    wg_barrier();
    const u16* Ab_ = &As[tt & 1][0];
    const u16* Bb_ = &Bs[tt & 1][0];
#pragma unroll
    for (int h = 0; h < 2; ++h) {
      const int so = h ? so1 : so0;
      short8 af[4], bf[4];
#pragma unroll
      for (int f = 0; f < 4; ++f)
        af[f] = *(const short8*)(Ab_ + (arow + f * 16 + lr) * 64 + so);
#pragma unroll
      for (int j = 0; j < 4; ++j)
        bf[j] = *(const short8*)(Bb_ + (brow + j * 16 + lr) * 64 + so);
      __builtin_amdgcn_s_setprio(1);
#pragma unroll
      for (int f = 0; f < 4; ++f)
#pragma unroll
        for (int j = 0; j < 4; ++j)
          acc[f][j] = __builtin_amdgcn_mfma_f32_16x16x32_bf16(af[f], bf[j], acc[f][j], 0, 0, 0);
      __builtin_amdgcn_s_setprio(0);
    }
    wg_barrier();
  }

  if (MODE == 1) {
    // fused epilogue: store exp(S); per-row sums over this block's 128 cols.
    float* sred = (float*)&As[0][0];  // [wx][128 rows]
#pragma unroll
    for (int f = 0; f < 4; ++f) {
#pragma unroll
      for (int r = 0; r < 4; ++r) {
        const int mr = m0 + arow + f * 16 + q * 4 + r;
        float s = 0.f;
#pragma unroll
        for (int j = 0; j < 4; ++j) {
          const int nc = n0 + brow + j * 16 + lr;
          float p = __expf(acc[f][j][r]);
          s += p;
          Cb[(long)blockIdx.z * sC + (long)mr * ldc + nc] = f32_to_bf16(p);
        }
#pragma unroll
        for (int o = 1; o < 16; o <<= 1) s += __shfl_xor(s, o);
        if (lr == 0) sred[wx * 128 + arow + f * 16 + q * 4 + r] = s;
      }
    }
    __syncthreads();
    if (wx == 0 && lr == 0) {
#pragma unroll
      for (int f = 0; f < 4; ++f)
#pragma unroll
        for (int r = 0; r < 4; ++r) {
          const int row = arow + f * 16 + q * 4 + r;
          psum[((long)blockIdx.z * 32 + bx) * 4096 + (m0 + row)] =
              sred[row] + sred[128 + row];
        }
    }
    return;
  }

  // epilogue: frag D col=lane&15, row=(lane>>4)*4+r
#pragma unroll
  for (int f = 0; f < 4; ++f) {
#pragma unroll
    for (int r = 0; r < 4; ++r) {
      const int mr = m0 + arow + f * 16 + q * 4 + r;
      float rowmul = 1.f, rowadd = 0.f;
      if (MODE == 2) rowmul = SinvP[(long)blockIdx.z * 4096 + mr];
      else if (biasM) rowadd = biasM[mr];
#pragma unroll
      for (int j = 0; j < 4; ++j) {
        const int nc = n0 + brow + j * 16 + lr;
        float vv = acc[f][j][r];
        if (MODE == 2) {
          vv *= rowmul;
        } else {
          vv += rowadd;
          if (biasN) vv += biasN[nc];
          vv *= scale;
        }
        Cb[(long)blockIdx.z * sC + (long)mr * ldc + nc] = f32_to_bf16(vv);
      }
    }
  }
}

// ---------------- combine per-tile row sums -> 1/sum ----------------
__global__ __launch_bounds__(256) void combine_sums(const float* __restrict__ ps,
                                                    float* __restrict__ Sinv) {
  const int row = blockIdx.x * 256 + threadIdx.x;  // 4096 rows
  const long z = blockIdx.y;
  const float* p = ps + z * 32 * 4096 + row;
  float s = 0.f;
#pragma unroll
  for (int i = 0; i < 32; ++i) s += p[(long)i * 4096];
  Sinv[z * 4096 + row] = 1.0f / s;
}

// ---------------- m97-style 128x128 GEMM (kept for proj: f32 out + residual) ----------------
template <int EPI>
__global__ __launch_bounds__(256) void gemm128(
    const u16* __restrict__ Ab, long sA, int lda,
    const u16* __restrict__ Bb, long sB, int ldb,
    void* __restrict__ Cb, long sC, int ldc,
    const float* __restrict__ biasM, const float* __restrict__ biasN,
    float scale, const float* __restrict__ res, long sR, int K) {
  const u16* A = Ab + (long)blockIdx.z * sA;
  const u16* B = Bb + (long)blockIdx.z * sB;
  const int m0 = blockIdx.y * 128, n0 = blockIdx.x * 128;
  const int t = threadIdx.x;
  const int wave = t >> 6, lane = t & 63;
  const int wy = wave >> 1, wx = wave & 1;
  const int lr = lane & 15, q = lane >> 4;
  __shared__ __align__(16) u16 As[128 * 32];
  __shared__ __align__(16) u16 Bs[128 * 32];
  f32x4 acc[4][4] = {};
  for (int k0 = 0; k0 < K; k0 += 32) {
#pragma unroll
    for (int c = 0; c < 2; ++c) {
      const int chunk = c * 256 + t;
      const int row = chunk >> 2, ko = (chunk & 3) << 3;
      const int ldsoff = (c * 256 + wave * 64) * 8;
      GLD_LDS16(A + (long)(m0 + row) * lda + (k0 + ko), As + ldsoff);
      GLD_LDS16(B + (long)(n0 + row) * ldb + (k0 + ko), Bs + ldsoff);
    }
    __syncthreads();
    short8 af[4], bf[4];
#pragma unroll
    for (int i = 0; i < 4; ++i)
      af[i] = *(const short8*)(&As[(wy * 64 + i * 16 + lr) * 32 + q * 8]);
#pragma unroll
    for (int j = 0; j < 4; ++j)
      bf[j] = *(const short8*)(&Bs[(wx * 64 + j * 16 + lr) * 32 + q * 8]);
#pragma unroll
    for (int i = 0; i < 4; ++i)
#pragma unroll
      for (int j = 0; j < 4; ++j)
        acc[i][j] = __builtin_amdgcn_mfma_f32_16x16x32_bf16(af[i], bf[j], acc[i][j], 0, 0, 0);
    __syncthreads();
  }
#pragma unroll
  for (int i = 0; i < 4; ++i) {
#pragma unroll
    for (int r = 0; r < 4; ++r) {
      const int mr = m0 + wy * 64 + i * 16 + q * 4 + r;
      const float bm = biasM ? biasM[mr] : 0.f;
#pragma unroll
      for (int j = 0; j < 4; ++j) {
        const int nc = n0 + wx * 64 + j * 16 + lr;
        float vv = acc[i][j][r] + bm;
        if (biasN) vv += biasN[nc];
        vv *= scale;
        const long off = (long)blockIdx.z * sC + (long)mr * ldc + nc;
        if (EPI == 0) {
          ((u16*)Cb)[off] = f32_to_bf16(vv);
        } else {
          ((float*)Cb)[off] = vv + res[(long)blockIdx.z * sR + (long)mr * ldc + nc];
        }
      }
    }
  }
}

extern "C" void kernel_launch(void* const* d_in, const int* in_sizes, int n_in,
                              void* d_out, int out_size, void* d_ws, size_t ws_size,
                              hipStream_t stream) {
  const float* x = (const float*)d_in[0];
  const float* gn_w = (const float*)d_in[1];
  const float* gn_b = (const float*)d_in[2];
  const float* q_w = (const float*)d_in[3];
  const float* q_b = (const float*)d_in[4];
  const float* k_w = (const float*)d_in[5];
  const float* k_b = (const float*)d_in[6];
  const float* v_w = (const float*)d_in[7];
  const float* v_b = (const float*)d_in[8];
  const float* p_w = (const float*)d_in[9];
  const float* p_b = (const float*)d_in[10];

  char* ws = (char*)d_ws;
  const size_t MB = 1ull << 20;
  u16* wqb = (u16*)(ws + 0);
  u16* wkb = (u16*)(ws + 512 * 1024);
  u16* wvb = (u16*)(ws + 1 * MB);
  u16* wpb = (u16*)(ws + 3 * MB / 2);
  u16* hb = (u16*)(ws + 2 * MB);   // 32 MB: hT, later reused as oT
  u16* vb = (u16*)(ws + 34 * MB);  // 32 MB: v [C][N]
  u16* Pb = (u16*)(ws + 66 * MB);  // 32*NB MB: score groups
  float2* gnstats = (float2*)(ws + 66 * MB);  // temporally disjoint from Pb
  u16* qb = (u16*)d_out;
  u16* kb = (u16*)d_out + 512L * 4096 * 8;
  u16* ob = hb;

  // batches per attention group; P region + ~4.2 MB softmax-sum tail
  int NB = 1;
  if (ws_size >= (66 + 8 * 32 + 5) * MB) NB = 8;
  else if (ws_size >= (66 + 4 * 32 + 5) * MB) NB = 4;
  else if (ws_size >= (66 + 2 * 32 + 5) * MB) NB = 2;

  // softmax sums after the P region: partials [NB][32][4096], then 1/S [NB][4096]
  float* psum = (float*)(ws + 66 * MB + (size_t)NB * 32 * MB);
  float* Si = psum + (size_t)NB * 32 * 4096;

  cvt4_f32_bf16<<<dim3(256, 4), 256, 0, stream>>>(q_w, k_w, v_w, p_w, wqb, wkb, wvb, wpb);
  gn_stats<<<256, 1024, 0, stream>>>(x, gnstats);
  gn_apply_t<<<dim3(4, 32, 8), 256, 0, stream>>>(x, gn_w, gn_b, gnstats, hb);

  const long sCN = 512L * 4096;
  const long sNN = 4096L * 4096;
  const float scale = 0.04419417382415922f;  // 512^-0.5, folded into q

  // qT[i][c'] = sum_c hT[i][c] qw[c'][c]; M=4096 N=512 K=512 -> grid (4,32,8)
  gemm128v2<0, 1><<<dim3(4, 32, 8), 256, 0, stream>>>(
      hb, sCN, 512, wqb, 0, 512, qb, sCN, 512, nullptr, q_b, scale, 512,
      nullptr, nullptr);
  gemm128v2<0, 1><<<dim3(4, 32, 8), 256, 0, stream>>>(
      hb, sCN, 512, wkb, 0, 512, kb, sCN, 512, nullptr, k_b, 1.0f, 512,
      nullptr, nullptr);
  // v[c'][j] = sum_c vw[c'][c] hT[j][c]; M=512 N=4096 K=512 -> grid (32,4,8)
  gemm128v2<0, 0><<<dim3(32, 4, 8), 256, 0, stream>>>(
      wvb, 0, 512, hb, sCN, 512, vb, sCN, 4096, v_b, nullptr, 1.0f, 512,
      nullptr, nullptr);

  for (int b0 = 0; b0 < 8; b0 += NB) {
    // P'[i][j] = exp(sum_c qT[i][c] kT[j][c]) + row partial sums; M=N=4096 K=512
    gemm128v2<1, 1><<<dim3(32, 32, NB), 256, 0, stream>>>(
        qb + b0 * sCN, sCN, 512, kb + b0 * sCN, sCN, 512, Pb, sNN, 4096,
        nullptr, nullptr, 1.0f, 512, psum, nullptr);
    combine_sums<<<dim3(16, NB), 256, 0, stream>>>(psum, Si);
    // oT[i][c'] = (sum_j P'[i][j] v[c'][j]) * Sinv[i]; M=4096 N=512 K=4096
    gemm128v2<2, 1><<<dim3(4, 32, NB), 256, 0, stream>>>(
        Pb, sNN, 4096, vb + b0 * sCN, sCN, 4096, ob + b0 * sCN, sCN, 512,
        nullptr, nullptr, 1.0f, 4096, nullptr, Si);
  }

  // out[c'][i] = sum_d pw[c'][d] oT[i][d] + pb[c'] + x; f32 + residual
  gemm128<1><<<dim3(32, 4, 8), 256, 0, stream>>>(
      wpb, 0, 512, ob, sCN, 512, (float*)d_out, sCN, 4096, p_b, nullptr, 1.0f,
      x, sCN, 512);
}